// Round 10
// baseline (125.837 us; speedup 1.0000x reference)
//
#include <hip/hip_runtime.h>
#include <hip/hip_bf16.h>

typedef __bf16 bf16_t;
typedef __bf16 bf16x8 __attribute__((ext_vector_type(8)));
typedef float f32x4 __attribute__((ext_vector_type(4)));
typedef float f32x16 __attribute__((ext_vector_type(16)));
typedef unsigned int u32;

#define MFMA16(A,B,C) __builtin_amdgcn_mfma_f32_16x16x32_bf16(A,B,C,0,0,0)
#define MFMA32(A,B,C) __builtin_amdgcn_mfma_f32_32x32x16_bf16(A,B,C,0,0,0)

constexpr int Bb = 4, Ll = 2048, Hh = 8, Ee = 64, Dd = 64;
constexpr int LDP = 72;   // prep/fallback kernels only
constexpr int MS = 128;   // band half-width (masked to -inf inside band)

static __device__ __forceinline__ bf16x8 cvt8(float4 a, float4 b) {
    bf16x8 t;
    t[0] = (bf16_t)a.x; t[1] = (bf16_t)a.y; t[2] = (bf16_t)a.z; t[3] = (bf16_t)a.w;
    t[4] = (bf16_t)b.x; t[5] = (bf16_t)b.y; t[6] = (bf16_t)b.z; t[7] = (bf16_t)b.w;
    return t;
}

static __device__ __forceinline__ u32 pkbf(float lo, float hi) {
    u32 d;
    asm("v_cvt_pk_bf16_f32 %0, %1, %2" : "=v"(d) : "v"(lo), "v"(hi));
    return d;
}

// raw v_exp_f32: inputs bounded (masked=-1e30 -> 0; live |s| <~ 30)
static __device__ __forceinline__ float fexp2(float x) {
    float r;
    asm("v_exp_f32 %0, %1" : "=v"(r) : "v"(x));
    return r;
}

static __device__ __forceinline__ f32x16 zero16() {
    f32x16 z;
    #pragma unroll
    for (int r = 0; r < 16; ++r) z[r] = 0.f;
    return z;
}

// ------ merged prep: K -> [b,h,l,e] bf16 ; V -> Vt [b,h,tile64,d,64] bf16 ---
__global__ __launch_bounds__(256) void prep(const float* __restrict__ K,
                                            const float* __restrict__ V,
                                            bf16_t* __restrict__ Kb,
                                            bf16_t* __restrict__ Vt) {
    __shared__ bf16_t VLp[Dd][LDP];
    if (blockIdx.x < 2048) {
        const int c = blockIdx.x * 256 + threadIdx.x;
        const int e0 = (c & 7) * 8;
        const int h  = (c >> 3) & (Hh - 1);
        const int l  = (c >> 6) & (Ll - 1);
        const int b  = c >> 17;
        const float* s = K + ((((size_t)b * Ll + l) * Hh + h) * Ee + e0);
        float4 f0 = ((const float4*)s)[0];
        float4 f1 = ((const float4*)s)[1];
        *(bf16x8*)(Kb + ((((size_t)b * Hh + h) * Ll + l) * Ee + e0)) = cvt8(f0, f1);
    } else {
        const int bb = blockIdx.x - 2048;
        const int bh = bb >> 5;
        const int t  = bb & 31;
        const int b = bh >> 3, h = bh & 7;
        {
            const int j  = threadIdx.x >> 2;
            const int d0 = (threadIdx.x & 3) * 16;
            const float* vp = V + (((size_t)(b * Ll + t * 64 + j)) * Hh + h) * Dd + d0;
            float4 x0 = ((const float4*)vp)[0], x1 = ((const float4*)vp)[1];
            float4 x2 = ((const float4*)vp)[2], x3 = ((const float4*)vp)[3];
            VLp[d0 +  0][j] = (bf16_t)x0.x; VLp[d0 +  1][j] = (bf16_t)x0.y;
            VLp[d0 +  2][j] = (bf16_t)x0.z; VLp[d0 +  3][j] = (bf16_t)x0.w;
            VLp[d0 +  4][j] = (bf16_t)x1.x; VLp[d0 +  5][j] = (bf16_t)x1.y;
            VLp[d0 +  6][j] = (bf16_t)x1.z; VLp[d0 +  7][j] = (bf16_t)x1.w;
            VLp[d0 +  8][j] = (bf16_t)x2.x; VLp[d0 +  9][j] = (bf16_t)x2.y;
            VLp[d0 + 10][j] = (bf16_t)x2.z; VLp[d0 + 11][j] = (bf16_t)x2.w;
            VLp[d0 + 12][j] = (bf16_t)x3.x; VLp[d0 + 13][j] = (bf16_t)x3.y;
            VLp[d0 + 14][j] = (bf16_t)x3.z; VLp[d0 + 15][j] = (bf16_t)x3.w;
        }
        __syncthreads();
        {
            const int d  = threadIdx.x >> 2;
            const int j0 = (threadIdx.x & 3) * 16;
            bf16x8 a0 = *(const bf16x8*)&VLp[d][j0];
            bf16x8 a1 = *(const bf16x8*)&VLp[d][j0 + 8];
            bf16_t* op = Vt + ((((size_t)bh * 32 + t) * 64 + d) * 64 + j0);
            *(bf16x8*)op = a0;
            *(bf16x8*)(op + 8) = a1;
        }
    }
}

// ---- main: register-direct K/V (no LDS, no barriers), 4 free-running waves -
// Each wave: 32 q-rows x full 64-k tiles. K double-buffered in regs
// (prefetch 1 tile ahead); V single-set issued early, consumed at PV.
__global__ __launch_bounds__(256, 2) void fattn9(const float* __restrict__ Q,
                                                 const bf16_t* __restrict__ Kb,
                                                 const bf16_t* __restrict__ Vt,
                                                 float* __restrict__ O) {
    const int tid = threadIdx.x;
    const int wv  = tid >> 6;
    const int ln  = tid & 63;
    const int l31 = ln & 31;
    const int lh  = ln >> 5;

    // XCD swizzle: 8 XCDs x 64 blocks; each XCD owns 4 consecutive bh
    const int bid = blockIdx.x;
    const int x   = bid & 7;
    const int o   = bid >> 3;             // 0..63
    const int bh  = x * 4 + (o >> 4);     // 0..31
    const int qt  = o & 15;
    const int q0  = qt * 128;
    const int wq0 = q0 + wv * 32;
    const int qq  = wq0 + l31;            // this lane's query row
    const int b = bh >> 3, h = bh & 7;

    const bf16_t* kbase = Kb + (size_t)bh * (Ll * 64);
    const bf16_t* vbase = Vt + (size_t)bh * (Ll * 64);
    const int loff = l31 * 64 + lh * 8;   // per-lane offset within a tile

    // Q fp32 -> scaled bf16 B-fragments (one-time)
    bf16x8 qreg[4];
    {
        const float SCL2 = 0.125f * 1.44269504f;
        const float* qp = Q + (((size_t)(b * Ll + qq)) * Hh + h) * Ee + lh * 8;
        #pragma unroll
        for (int ks = 0; ks < 4; ++ks) {
            float4 f0 = *(const float4*)(qp + ks * 16);
            float4 f1 = *(const float4*)(qp + ks * 16 + 4);
            f0.x *= SCL2; f0.y *= SCL2; f0.z *= SCL2; f0.w *= SCL2;
            f1.x *= SCL2; f1.y *= SCL2; f1.z *= SCL2; f1.w *= SCL2;
            qreg[ks] = cvt8(f0, f1);
        }
    }

    f32x16 acc0 = zero16(), acc1 = zero16();
    float psum = 0.f;

    const int s0t = qt * 2;    // 64-tiles s0t, s0t+1 fully masked -> skipped
    #define TILEOF(i) ((i) + ((i) >= s0t ? 2 : 0))

    // K register sets (named double-buffer) + V single set
    bf16x8 kA[8], kB[8], vf[8];

    #define LOADSET(dst, base, kt_) do {                                          \
        const bf16_t* _p = (base) + (size_t)(kt_) * 4096 + loff;                  \
        _Pragma("unroll")                                                         \
        for (int _su = 0; _su < 2; ++_su)                                         \
            _Pragma("unroll")                                                     \
            for (int _ks = 0; _ks < 4; ++_ks)                                     \
                dst[_su * 4 + _ks] =                                              \
                    *(const bf16x8*)(_p + _su * 2048 + _ks * 16);                 \
    } while (0)

    // one tile of work using K set `kset` and current vf
    #define TILE(kset, k0_) do {                                                  \
        f32x16 s0v = zero16(), s1v = zero16();                                    \
        __builtin_amdgcn_s_setprio(1);                                            \
        _Pragma("unroll")                                                         \
        for (int ks = 0; ks < 4; ++ks) {                                          \
            s0v = MFMA32(kset[ks],     qreg[ks], s0v);                            \
            s1v = MFMA32(kset[4 + ks], qreg[ks], s1v);                            \
        }                                                                         \
        __builtin_amdgcn_s_setprio(0);                                            \
        {                                                                         \
            const int d0_ = wq0 - (k0_);                                          \
            if (d0_ > -159 && d0_ < 159) {                                        \
                _Pragma("unroll")                                                 \
                for (int r = 0; r < 16; ++r) {                                    \
                    const int k = (k0_) + 4 * lh + ((r & 3) + 8 * (r >> 2));      \
                    const int dlt = qq - k;                                       \
                    if (dlt > -MS && dlt < MS) s0v[r] = -1e30f;                   \
                }                                                                 \
            }                                                                     \
            const int d1_ = wq0 - ((k0_) + 32);                                   \
            if (d1_ > -159 && d1_ < 159) {                                        \
                _Pragma("unroll")                                                 \
                for (int r = 0; r < 16; ++r) {                                    \
                    const int k = (k0_) + 32 + 4 * lh + ((r & 3) + 8 * (r >> 2)); \
                    const int dlt = qq - k;                                       \
                    if (dlt > -MS && dlt < MS) s1v[r] = -1e30f;                   \
                }                                                                 \
            }                                                                     \
        }                                                                         \
        bf16x8 pf[4];                                                             \
        {                                                                         \
            float p[16];                                                          \
            _Pragma("unroll")                                                     \
            for (int r = 0; r < 16; ++r) p[r] = fexp2(s0v[r]);                    \
            psum += ((p[0] + p[1]) + (p[2] + p[3])) +                             \
                    ((p[4] + p[5]) + (p[6] + p[7])) +                             \
                    (((p[8] + p[9]) + (p[10] + p[11])) +                          \
                     ((p[12] + p[13]) + (p[14] + p[15])));                        \
            u32 x0 = pkbf(p[0], p[1]),   x1 = pkbf(p[2], p[3]);                   \
            u32 x2 = pkbf(p[4], p[5]),   x3 = pkbf(p[6], p[7]);                   \
            u32 x4 = pkbf(p[8], p[9]),   x5 = pkbf(p[10], p[11]);                 \
            u32 x6 = pkbf(p[12], p[13]), x7 = pkbf(p[14], p[15]);                 \
            asm volatile("v_permlane32_swap_b32 %0, %1" : "+v"(x0), "+v"(x2));    \
            asm volatile("v_permlane32_swap_b32 %0, %1" : "+v"(x1), "+v"(x3));    \
            asm volatile("v_permlane32_swap_b32 %0, %1" : "+v"(x4), "+v"(x6));    \
            asm volatile("v_permlane32_swap_b32 %0, %1" : "+v"(x5), "+v"(x7));    \
            union { u32 w[4]; bf16x8 v; } u0, u1;                                 \
            u0.w[0] = x0; u0.w[1] = x1; u0.w[2] = x2; u0.w[3] = x3;               \
            u1.w[0] = x4; u1.w[1] = x5; u1.w[2] = x6; u1.w[3] = x7;               \
            pf[0] = u0.v; pf[1] = u1.v;                                           \
        }                                                                         \
        {                                                                         \
            float p[16];                                                          \
            _Pragma("unroll")                                                     \
            for (int r = 0; r < 16; ++r) p[r] = fexp2(s1v[r]);                    \
            psum += ((p[0] + p[1]) + (p[2] + p[3])) +                             \
                    ((p[4] + p[5]) + (p[6] + p[7])) +                             \
                    (((p[8] + p[9]) + (p[10] + p[11])) +                          \
                     ((p[12] + p[13]) + (p[14] + p[15])));                        \
            u32 x0 = pkbf(p[0], p[1]),   x1 = pkbf(p[2], p[3]);                   \
            u32 x2 = pkbf(p[4], p[5]),   x3 = pkbf(p[6], p[7]);                   \
            u32 x4 = pkbf(p[8], p[9]),   x5 = pkbf(p[10], p[11]);                 \
            u32 x6 = pkbf(p[12], p[13]), x7 = pkbf(p[14], p[15]);                 \
            asm volatile("v_permlane32_swap_b32 %0, %1" : "+v"(x0), "+v"(x2));    \
            asm volatile("v_permlane32_swap_b32 %0, %1" : "+v"(x1), "+v"(x3));    \
            asm volatile("v_permlane32_swap_b32 %0, %1" : "+v"(x4), "+v"(x6));    \
            asm volatile("v_permlane32_swap_b32 %0, %1" : "+v"(x5), "+v"(x7));    \
            union { u32 w[4]; bf16x8 v; } u0, u1;                                 \
            u0.w[0] = x0; u0.w[1] = x1; u0.w[2] = x2; u0.w[3] = x3;               \
            u1.w[0] = x4; u1.w[1] = x5; u1.w[2] = x6; u1.w[3] = x7;               \
            pf[2] = u0.v; pf[3] = u1.v;                                           \
        }                                                                         \
        __builtin_amdgcn_s_setprio(1);                                            \
        _Pragma("unroll")                                                         \
        for (int ks = 0; ks < 4; ++ks) {                                          \
            acc0 = MFMA32(pf[ks], vf[ks],     acc0);                              \
            acc1 = MFMA32(pf[ks], vf[4 + ks], acc1);                              \
        }                                                                         \
        __builtin_amdgcn_s_setprio(0);                                            \
    } while (0)

    LOADSET(kA, kbase, TILEOF(0));

    #pragma unroll 1
    for (int ii = 0; ii < 30; ii += 2) {
        {
            const int kt_ = TILEOF(ii);
            const int k0 = kt_ * 64;
            LOADSET(vf, vbase, kt_);                       // V for this tile
            if (ii + 1 < 30) LOADSET(kB, kbase, TILEOF(ii + 1));  // K prefetch
            TILE(kA, k0);
        }
        {
            const int kt_ = TILEOF(ii + 1);
            const int k0 = kt_ * 64;
            LOADSET(vf, vbase, kt_);
            if (ii + 2 < 30) LOADSET(kA, kbase, TILEOF(ii + 2));
            TILE(kB, k0);
        }
    }
    #undef TILE
    #undef LOADSET
    #undef TILEOF

    // ---- epilogue: lane-local psum -> full row sum -> normalize ----
    psum += __shfl_xor(psum, 32);          // combine the two lh k-halves
    const float inv = 1.0f / psum;         // lane l31 holds q-row wq0+l31's inv
    #pragma unroll
    for (int r = 0; r < 16; ++r) {
        const int rr = (r & 3) + 8 * (r >> 2) + 4 * lh;
        const float ir = __shfl(inv, rr);
        float* op = O + ((size_t)(b * Ll + wq0 + rr) * Hh + h) * Dd + l31;
        op[0]  = acc0[r] * ir;
        op[32] = acc1[r] * ir;
    }
}

// ---------------- fallback (fp32 inputs, online softmax, 16x16) -------------
__global__ __launch_bounds__(256, 2) void fattn_f32(const float* __restrict__ Q,
                                                    const float* __restrict__ K,
                                                    const float* __restrict__ V,
                                                    float* __restrict__ O) {
    __shared__ __align__(16) bf16_t Klds[64][LDP];
    __shared__ __align__(16) bf16_t Vtlds[Dd][LDP];
    __shared__ __align__(16) bf16_t Plds[4][16][LDP];

    const int tid = threadIdx.x;
    const int wv  = tid >> 6;
    const int ln  = tid & 63;
    const int l15 = ln & 15;
    const int g   = ln >> 4;

    const int nqt = Ll / 64;
    const int bid = blockIdx.x;
    const int qt  = bid % nqt;
    const int bh  = bid / nqt;
    const int b   = bh >> 3;
    const int h   = bh & 7;
    const int q0  = qt * 64;

    const float SCL2 = 0.125f * 1.44269504f;

    bf16x8 qf[2];
    {
        const float* qp = Q + (((size_t)(b * Ll + q0 + wv * 16 + l15)) * Hh + h) * Ee + g * 8;
        #pragma unroll
        for (int ks = 0; ks < 2; ++ks) {
            float4 f0 = *(const float4*)(qp + 32 * ks);
            float4 f1 = *(const float4*)(qp + 32 * ks + 4);
            qf[ks] = cvt8(f0, f1);
        }
    }

    f32x4 acc[4];
    #pragma unroll
    for (int ct = 0; ct < 4; ++ct) acc[ct] = (f32x4){0.f, 0.f, 0.f, 0.f};
    float m2[4], lsum[4];
    #pragma unroll
    for (int r = 0; r < 4; ++r) { m2[r] = -1e30f; lsum[r] = 0.f; }

    for (int k0 = 0; k0 < Ll; k0 += 64) {
        const int dd = k0 - q0;
        if (dd >= -64 && dd <= 64) continue;
        const bool needmask = (dd == 128) || (dd == -128);

        __syncthreads();
        {
            const int j  = tid >> 2;
            const int c0 = (tid & 3) << 4;
            const float* kp = K + (((size_t)(b * Ll + k0 + j)) * Hh + h) * Ee + c0;
            const float* vp = V + (((size_t)(b * Ll + k0 + j)) * Hh + h) * Dd + c0;
            float4 a0 = ((const float4*)kp)[0], a1 = ((const float4*)kp)[1];
            float4 a2 = ((const float4*)kp)[2], a3 = ((const float4*)kp)[3];
            *(bf16x8*)&Klds[j][c0]     = cvt8(a0, a1);
            *(bf16x8*)&Klds[j][c0 + 8] = cvt8(a2, a3);
            float4 b0 = ((const float4*)vp)[0], b1 = ((const float4*)vp)[1];
            float4 b2 = ((const float4*)vp)[2], b3 = ((const float4*)vp)[3];
            Vtlds[c0 +  0][j] = (bf16_t)b0.x; Vtlds[c0 +  1][j] = (bf16_t)b0.y;
            Vtlds[c0 +  2][j] = (bf16_t)b0.z; Vtlds[c0 +  3][j] = (bf16_t)b0.w;
            Vtlds[c0 +  4][j] = (bf16_t)b1.x; Vtlds[c0 +  5][j] = (bf16_t)b1.y;
            Vtlds[c0 +  6][j] = (bf16_t)b1.z; Vtlds[c0 +  7][j] = (bf16_t)b1.w;
            Vtlds[c0 +  8][j] = (bf16_t)b2.x; Vtlds[c0 +  9][j] = (bf16_t)b2.y;
            Vtlds[c0 + 10][j] = (bf16_t)b2.z; Vtlds[c0 + 11][j] = (bf16_t)b2.w;
            Vtlds[c0 + 12][j] = (bf16_t)b3.x; Vtlds[c0 + 13][j] = (bf16_t)b3.y;
            Vtlds[c0 + 14][j] = (bf16_t)b3.z; Vtlds[c0 + 15][j] = (bf16_t)b3.w;
        }
        __syncthreads();

        f32x4 s[4];
        #pragma unroll
        for (int ct = 0; ct < 4; ++ct) {
            f32x4 z = (f32x4){0.f, 0.f, 0.f, 0.f};
            #pragma unroll
            for (int ks = 0; ks < 2; ++ks) {
                bf16x8 kf = *(const bf16x8*)&Klds[ct * 16 + l15][ks * 32 + g * 8];
                z = MFMA16(qf[ks], kf, z);
            }
            s[ct] = z;
        }

        float lg[4][4];
        #pragma unroll
        for (int ct = 0; ct < 4; ++ct)
            #pragma unroll
            for (int r = 0; r < 4; ++r)
                lg[ct][r] = s[ct][r] * SCL2;

        if (needmask) {
            const int irow = q0 + wv * 16 + g * 4;
            #pragma unroll
            for (int ct = 0; ct < 4; ++ct) {
                const int j = k0 + ct * 16 + l15;
                #pragma unroll
                for (int r = 0; r < 4; ++r) {
                    int diff = irow + r - j;
                    diff = diff < 0 ? -diff : diff;
                    if (diff < MS) lg[ct][r] = -1e30f;
                }
            }
        }

        #pragma unroll
        for (int r = 0; r < 4; ++r) {
            float mx = fmaxf(fmaxf(lg[0][r], lg[1][r]), fmaxf(lg[2][r], lg[3][r]));
            #pragma unroll
            for (int off = 1; off < 16; off <<= 1) mx = fmaxf(mx, __shfl_xor(mx, off));
            const float mnew = fmaxf(m2[r], mx);
            const float c = exp2f(m2[r] - mnew);
            m2[r] = mnew;
            #pragma unroll
            for (int ct = 0; ct < 4; ++ct) acc[ct][r] *= c;
            float ps = 0.f;
            #pragma unroll
            for (int ct = 0; ct < 4; ++ct) {
                float p = exp2f(lg[ct][r] - mnew);
                bf16_t pb = (bf16_t)p;
                Plds[wv][g * 4 + r][ct * 16 + l15] = pb;
                ps += (float)pb;
            }
            #pragma unroll
            for (int off = 1; off < 16; off <<= 1) ps += __shfl_xor(ps, off);
            lsum[r] = lsum[r] * c + ps;
        }

        __syncthreads();

        #pragma unroll
        for (int ks = 0; ks < 2; ++ks) {
            bf16x8 pfr = *(const bf16x8*)&Plds[wv][l15][ks * 32 + g * 8];
            #pragma unroll
            for (int ct = 0; ct < 4; ++ct) {
                bf16x8 vfl = *(const bf16x8*)&Vtlds[ct * 16 + l15][ks * 32 + g * 8];
                acc[ct] = MFMA16(pfr, vfl, acc[ct]);
            }
        }
    }

    #pragma unroll
    for (int r = 0; r < 4; ++r) {
        const float inv = 1.0f / lsum[r];
        const size_t row = (size_t)(b * Ll + q0 + wv * 16 + g * 4 + r);
        float* op = O + (row * Hh + h) * Dd;
        #pragma unroll
        for (int ct = 0; ct < 4; ++ct)
            op[ct * 16 + l15] = acc[ct][r] * inv;
    }
}

extern "C" void kernel_launch(void* const* d_in, const int* in_sizes, int n_in,
                              void* d_out, int out_size, void* d_ws, size_t ws_size,
                              hipStream_t stream) {
    const float* Q = (const float*)d_in[0];
    const float* K = (const float*)d_in[1];
    const float* V = (const float*)d_in[2];
    float* O = (float*)d_out;

    const size_t nelem = (size_t)Bb * Hh * Ll * Ee;      // 4.19M per tensor
    const size_t need  = nelem * 2 * 2;                  // Kb + Vt bf16

    if (ws_size >= need) {
        bf16_t* Kb = (bf16_t*)d_ws;
        bf16_t* Vt = Kb + nelem;
        prep<<<dim3(3072), dim3(256), 0, stream>>>(K, V, Kb, Vt);
        fattn9<<<dim3(512), dim3(256), 0, stream>>>(Q, Kb, Vt, O);
    } else {
        fattn_f32<<<dim3(Bb * Hh * 32), dim3(256), 0, stream>>>(Q, K, V, O);
    }
}

// Round 11
// 63.345 us; speedup vs baseline: 1.9865x; 1.9865x over previous
//
#include <hip/hip_runtime.h>
#include <hip/hip_bf16.h>

typedef __bf16 bf16_t;
typedef __bf16 bf16x8 __attribute__((ext_vector_type(8)));
typedef float f32x4 __attribute__((ext_vector_type(4)));
typedef float f32x16 __attribute__((ext_vector_type(16)));
typedef unsigned int u32;

#define MFMA16(A,B,C) __builtin_amdgcn_mfma_f32_16x16x32_bf16(A,B,C,0,0,0)
#define MFMA32(A,B,C) __builtin_amdgcn_mfma_f32_32x32x16_bf16(A,B,C,0,0,0)

constexpr int Bb = 4, Ll = 2048, Hh = 8, Ee = 64, Dd = 64;
constexpr int LDP = 72;   // prep/fallback kernels only
constexpr int MS = 128;   // band half-width (masked to -inf inside band)

static __device__ __forceinline__ bf16x8 cvt8(float4 a, float4 b) {
    bf16x8 t;
    t[0] = (bf16_t)a.x; t[1] = (bf16_t)a.y; t[2] = (bf16_t)a.z; t[3] = (bf16_t)a.w;
    t[4] = (bf16_t)b.x; t[5] = (bf16_t)b.y; t[6] = (bf16_t)b.z; t[7] = (bf16_t)b.w;
    return t;
}

static __device__ __forceinline__ u32 pkbf(float lo, float hi) {
    u32 d;
    asm("v_cvt_pk_bf16_f32 %0, %1, %2" : "=v"(d) : "v"(lo), "v"(hi));
    return d;
}

// raw v_exp_f32: inputs bounded (masked=-1e30 -> 0; live |s| <~ 30)
static __device__ __forceinline__ float fexp2(float x) {
    float r;
    asm("v_exp_f32 %0, %1" : "=v"(r) : "v"(x));
    return r;
}

static __device__ __forceinline__ f32x16 zero16() {
    f32x16 z;
    #pragma unroll
    for (int r = 0; r < 16; ++r) z[r] = 0.f;
    return z;
}

// ------ merged prep: K -> [b,h,l,e] bf16 ; V -> Vt [b,h,tile64,d,64] bf16 ---
__global__ __launch_bounds__(256) void prep(const float* __restrict__ K,
                                            const float* __restrict__ V,
                                            bf16_t* __restrict__ Kb,
                                            bf16_t* __restrict__ Vt) {
    __shared__ bf16_t VLp[Dd][LDP];
    if (blockIdx.x < 2048) {
        const int c = blockIdx.x * 256 + threadIdx.x;
        const int e0 = (c & 7) * 8;
        const int h  = (c >> 3) & (Hh - 1);
        const int l  = (c >> 6) & (Ll - 1);
        const int b  = c >> 17;
        const float* s = K + ((((size_t)b * Ll + l) * Hh + h) * Ee + e0);
        float4 f0 = ((const float4*)s)[0];
        float4 f1 = ((const float4*)s)[1];
        *(bf16x8*)(Kb + ((((size_t)b * Hh + h) * Ll + l) * Ee + e0)) = cvt8(f0, f1);
    } else {
        const int bb = blockIdx.x - 2048;
        const int bh = bb >> 5;
        const int t  = bb & 31;
        const int b = bh >> 3, h = bh & 7;
        {
            const int j  = threadIdx.x >> 2;
            const int d0 = (threadIdx.x & 3) * 16;
            const float* vp = V + (((size_t)(b * Ll + t * 64 + j)) * Hh + h) * Dd + d0;
            float4 x0 = ((const float4*)vp)[0], x1 = ((const float4*)vp)[1];
            float4 x2 = ((const float4*)vp)[2], x3 = ((const float4*)vp)[3];
            VLp[d0 +  0][j] = (bf16_t)x0.x; VLp[d0 +  1][j] = (bf16_t)x0.y;
            VLp[d0 +  2][j] = (bf16_t)x0.z; VLp[d0 +  3][j] = (bf16_t)x0.w;
            VLp[d0 +  4][j] = (bf16_t)x1.x; VLp[d0 +  5][j] = (bf16_t)x1.y;
            VLp[d0 +  6][j] = (bf16_t)x1.z; VLp[d0 +  7][j] = (bf16_t)x1.w;
            VLp[d0 +  8][j] = (bf16_t)x2.x; VLp[d0 +  9][j] = (bf16_t)x2.y;
            VLp[d0 + 10][j] = (bf16_t)x2.z; VLp[d0 + 11][j] = (bf16_t)x2.w;
            VLp[d0 + 12][j] = (bf16_t)x3.x; VLp[d0 + 13][j] = (bf16_t)x3.y;
            VLp[d0 + 14][j] = (bf16_t)x3.z; VLp[d0 + 15][j] = (bf16_t)x3.w;
        }
        __syncthreads();
        {
            const int d  = threadIdx.x >> 2;
            const int j0 = (threadIdx.x & 3) * 16;
            bf16x8 a0 = *(const bf16x8*)&VLp[d][j0];
            bf16x8 a1 = *(const bf16x8*)&VLp[d][j0 + 8];
            bf16_t* op = Vt + ((((size_t)bh * 32 + t) * 64 + d) * 64 + j0);
            *(bf16x8*)op = a0;
            *(bf16x8*)(op + 8) = a1;
        }
    }
}

// ---- main: 8 waves / 256 q-rows per block (two q-tiles of the same bh) ----
// Each staged K/V tile feeds 8 waves (2x the compute per staged byte vs r7).
// All 32 tiles processed; the band mask itself zeroes each wave's 2 fully-
// banded tiles (|i-j| <= 127 for every element -> p = 0 exactly).
__global__ __launch_bounds__(512, 1) void fattn10(const float* __restrict__ Q,
                                                  const bf16_t* __restrict__ Kb,
                                                  const bf16_t* __restrict__ Vt,
                                                  float* __restrict__ O) {
    __shared__ __align__(16) bf16_t KL[2 * 4096];
    __shared__ __align__(16) bf16_t VL[2 * 4096];

    const int tid = threadIdx.x;
    const int wv  = tid >> 6;          // 0..7
    const int ln  = tid & 63;
    const int l31 = ln & 31;
    const int lh  = ln >> 5;

    // XCD swizzle: 8 XCDs x 32 blocks; each XCD owns 4 consecutive bh
    const int bid = blockIdx.x;
    const int x   = bid & 7;
    const int o   = bid >> 3;             // 0..31
    const int bh  = x * 4 + (o >> 3);     // 0..31
    const int p   = o & 7;                // q-pair index
    const int qt  = (wv < 4) ? p : (p + 8);
    const int wq0 = qt * 128 + (wv & 3) * 32;
    const int qq  = wq0 + l31;            // this lane's query row
    const int b = bh >> 3, h = bh & 7;

    const bf16_t* kbase = Kb + (size_t)bh * (Ll * 64);
    const bf16_t* vbase = Vt + (size_t)bh * (Ll * 64);

    // Q fp32 -> scaled bf16 B-fragments (one-time)
    bf16x8 qreg[4];
    {
        const float SCL2 = 0.125f * 1.44269504f;
        const float* qp = Q + (((size_t)(b * Ll + qq)) * Hh + h) * Ee + lh * 8;
        #pragma unroll
        for (int ks = 0; ks < 4; ++ks) {
            float4 f0 = *(const float4*)(qp + ks * 16);
            float4 f1 = *(const float4*)(qp + ks * 16 + 4);
            f0.x *= SCL2; f0.y *= SCL2; f0.z *= SCL2; f0.w *= SCL2;
            f1.x *= SCL2; f1.y *= SCL2; f1.z *= SCL2; f1.w *= SCL2;
            qreg[ks] = cvt8(f0, f1);
        }
    }

    bf16x8 ones;
    #pragma unroll
    for (int e = 0; e < 8; ++e) ones[e] = (bf16_t)1.0f;

    f32x16 acc0 = zero16(), acc1 = zero16(), accP = zero16();

    // staging: 512 threads x (1 K-chunk + 1 V-chunk) of 16B per 64-k tile.
    // Source pre-swizzled so linear DMA realizes chunk ^= (row&7) in LDS.
    const int srow = tid >> 3;                               // 0..63
    const int soff = srow * 64 + (((tid & 7) ^ (srow & 7)) << 3);
    const int ldst = tid * 8;

    #define STAGE(nxt, kt_) do {                                                   \
        __builtin_amdgcn_global_load_lds((const void*)(kbase + (size_t)(kt_) * 4096\
                                         + soff), (void*)(KL + (nxt) * 4096 + ldst), 16, 0, 0); \
        __builtin_amdgcn_global_load_lds((const void*)(vbase + (size_t)(kt_) * 4096\
                                         + soff), (void*)(VL + (nxt) * 4096 + ldst), 16, 0, 0); \
    } while (0)

    STAGE(0, 0);

    for (int i = 0; i < 32; ++i) {
        const int k0 = i * 64;

        if (i + 1 < 32) {
            STAGE((i + 1) & 1, i + 1);
            asm volatile("s_waitcnt vmcnt(2)" ::: "memory");
        } else {
            asm volatile("s_waitcnt vmcnt(0)" ::: "memory");
        }
        __builtin_amdgcn_s_barrier();

        const int bo = (i & 1) * 4096;

        // ---- S^T = K Q^T : two 32x32 subtiles ----
        f32x16 s0v = zero16(), s1v = zero16();
        __builtin_amdgcn_s_setprio(1);
        #pragma unroll
        for (int ks = 0; ks < 4; ++ks) {
            const int cc = (((2 * ks + lh) ^ (l31 & 7)) << 3);
            bf16x8 ka0 = *(const bf16x8*)&KL[bo + l31 * 64 + cc];
            bf16x8 ka1 = *(const bf16x8*)&KL[bo + (32 + l31) * 64 + cc];
            s0v = MFMA32(ka0, qreg[ks], s0v);
            s1v = MFMA32(ka1, qreg[ks], s1v);
        }
        __builtin_amdgcn_s_setprio(0);

        // ---- band mask (also zeroes this wave's 2 fully-banded tiles) ----
        {
            const int d0_ = wq0 - k0;
            if (d0_ > -159 && d0_ < 159) {
                #pragma unroll
                for (int r = 0; r < 16; ++r) {
                    const int k = k0 + 4 * lh + ((r & 3) + 8 * (r >> 2));
                    const int dlt = qq - k;
                    if (dlt > -MS && dlt < MS) s0v[r] = -1e30f;
                }
            }
            const int d1_ = wq0 - (k0 + 32);
            if (d1_ > -159 && d1_ < 159) {
                #pragma unroll
                for (int r = 0; r < 16; ++r) {
                    const int k = k0 + 32 + 4 * lh + ((r & 3) + 8 * (r >> 2));
                    const int dlt = qq - k;
                    if (dlt > -MS && dlt < MS) s1v[r] = -1e30f;
                }
            }
        }

        // ---- p = exp2(s), pack into PV A-fragments ----
        bf16x8 pf[4];
        {
            float pp[16];
            #pragma unroll
            for (int r = 0; r < 16; ++r) pp[r] = fexp2(s0v[r]);
            u32 x0 = pkbf(pp[0], pp[1]),   x1 = pkbf(pp[2], pp[3]);
            u32 x2 = pkbf(pp[4], pp[5]),   x3 = pkbf(pp[6], pp[7]);
            u32 x4 = pkbf(pp[8], pp[9]),   x5 = pkbf(pp[10], pp[11]);
            u32 x6 = pkbf(pp[12], pp[13]), x7 = pkbf(pp[14], pp[15]);
            asm volatile("v_permlane32_swap_b32 %0, %1" : "+v"(x0), "+v"(x2));
            asm volatile("v_permlane32_swap_b32 %0, %1" : "+v"(x1), "+v"(x3));
            asm volatile("v_permlane32_swap_b32 %0, %1" : "+v"(x4), "+v"(x6));
            asm volatile("v_permlane32_swap_b32 %0, %1" : "+v"(x5), "+v"(x7));
            union { u32 w[4]; bf16x8 v; } u0, u1;
            u0.w[0] = x0; u0.w[1] = x1; u0.w[2] = x2; u0.w[3] = x3;
            u1.w[0] = x4; u1.w[1] = x5; u1.w[2] = x6; u1.w[3] = x7;
            pf[0] = u0.v; pf[1] = u1.v;
        }
        {
            float pp[16];
            #pragma unroll
            for (int r = 0; r < 16; ++r) pp[r] = fexp2(s1v[r]);
            u32 x0 = pkbf(pp[0], pp[1]),   x1 = pkbf(pp[2], pp[3]);
            u32 x2 = pkbf(pp[4], pp[5]),   x3 = pkbf(pp[6], pp[7]);
            u32 x4 = pkbf(pp[8], pp[9]),   x5 = pkbf(pp[10], pp[11]);
            u32 x6 = pkbf(pp[12], pp[13]), x7 = pkbf(pp[14], pp[15]);
            asm volatile("v_permlane32_swap_b32 %0, %1" : "+v"(x0), "+v"(x2));
            asm volatile("v_permlane32_swap_b32 %0, %1" : "+v"(x1), "+v"(x3));
            asm volatile("v_permlane32_swap_b32 %0, %1" : "+v"(x4), "+v"(x6));
            asm volatile("v_permlane32_swap_b32 %0, %1" : "+v"(x5), "+v"(x7));
            union { u32 w[4]; bf16x8 v; } u0, u1;
            u0.w[0] = x0; u0.w[1] = x1; u0.w[2] = x2; u0.w[3] = x3;
            u1.w[0] = x4; u1.w[1] = x5; u1.w[2] = x6; u1.w[3] = x7;
            pf[2] = u0.v; pf[3] = u1.v;
        }

        // ---- O += P V ; row-sums via ones-MFMA ----
        __builtin_amdgcn_s_setprio(1);
        #pragma unroll
        for (int ks = 0; ks < 4; ++ks) {
            const int cc = (((2 * ks + lh) ^ (l31 & 7)) << 3);
            bf16x8 vf0 = *(const bf16x8*)&VL[bo + l31 * 64 + cc];
            bf16x8 vf1 = *(const bf16x8*)&VL[bo + (32 + l31) * 64 + cc];
            acc0 = MFMA32(pf[ks], vf0, acc0);
            acc1 = MFMA32(pf[ks], vf1, acc1);
            accP = MFMA32(pf[ks], ones, accP);
        }
        __builtin_amdgcn_s_setprio(0);

        __builtin_amdgcn_s_barrier();
    }
    #undef STAGE

    // ---- epilogue: accP[r] = row-sum for the same row as acc*[r] ----
    #pragma unroll
    for (int r = 0; r < 16; ++r) {
        const int rr = (r & 3) + 8 * (r >> 2) + 4 * lh;
        const float ir = 1.0f / accP[r];
        float* op = O + ((size_t)(b * Ll + wq0 + rr) * Hh + h) * Dd + l31;
        op[0]  = acc0[r] * ir;
        op[32] = acc1[r] * ir;
    }
}

// ---------------- fallback (fp32 inputs, online softmax, 16x16) -------------
__global__ __launch_bounds__(256, 2) void fattn_f32(const float* __restrict__ Q,
                                                    const float* __restrict__ K,
                                                    const float* __restrict__ V,
                                                    float* __restrict__ O) {
    __shared__ __align__(16) bf16_t Klds[64][LDP];
    __shared__ __align__(16) bf16_t Vtlds[Dd][LDP];
    __shared__ __align__(16) bf16_t Plds[4][16][LDP];

    const int tid = threadIdx.x;
    const int wv  = tid >> 6;
    const int ln  = tid & 63;
    const int l15 = ln & 15;
    const int g   = ln >> 4;

    const int nqt = Ll / 64;
    const int bid = blockIdx.x;
    const int qt  = bid % nqt;
    const int bh  = bid / nqt;
    const int b   = bh >> 3;
    const int h   = bh & 7;
    const int q0  = qt * 64;

    const float SCL2 = 0.125f * 1.44269504f;

    bf16x8 qf[2];
    {
        const float* qp = Q + (((size_t)(b * Ll + q0 + wv * 16 + l15)) * Hh + h) * Ee + g * 8;
        #pragma unroll
        for (int ks = 0; ks < 2; ++ks) {
            float4 f0 = *(const float4*)(qp + 32 * ks);
            float4 f1 = *(const float4*)(qp + 32 * ks + 4);
            qf[ks] = cvt8(f0, f1);
        }
    }

    f32x4 acc[4];
    #pragma unroll
    for (int ct = 0; ct < 4; ++ct) acc[ct] = (f32x4){0.f, 0.f, 0.f, 0.f};
    float m2[4], lsum[4];
    #pragma unroll
    for (int r = 0; r < 4; ++r) { m2[r] = -1e30f; lsum[r] = 0.f; }

    for (int k0 = 0; k0 < Ll; k0 += 64) {
        const int dd = k0 - q0;
        if (dd >= -64 && dd <= 64) continue;
        const bool needmask = (dd == 128) || (dd == -128);

        __syncthreads();
        {
            const int j  = tid >> 2;
            const int c0 = (tid & 3) << 4;
            const float* kp = K + (((size_t)(b * Ll + k0 + j)) * Hh + h) * Ee + c0;
            const float* vp = V + (((size_t)(b * Ll + k0 + j)) * Hh + h) * Dd + c0;
            float4 a0 = ((const float4*)kp)[0], a1 = ((const float4*)kp)[1];
            float4 a2 = ((const float4*)kp)[2], a3 = ((const float4*)kp)[3];
            *(bf16x8*)&Klds[j][c0]     = cvt8(a0, a1);
            *(bf16x8*)&Klds[j][c0 + 8] = cvt8(a2, a3);
            float4 b0 = ((const float4*)vp)[0], b1 = ((const float4*)vp)[1];
            float4 b2 = ((const float4*)vp)[2], b3 = ((const float4*)vp)[3];
            Vtlds[c0 +  0][j] = (bf16_t)b0.x; Vtlds[c0 +  1][j] = (bf16_t)b0.y;
            Vtlds[c0 +  2][j] = (bf16_t)b0.z; Vtlds[c0 +  3][j] = (bf16_t)b0.w;
            Vtlds[c0 +  4][j] = (bf16_t)b1.x; Vtlds[c0 +  5][j] = (bf16_t)b1.y;
            Vtlds[c0 +  6][j] = (bf16_t)b1.z; Vtlds[c0 +  7][j] = (bf16_t)b1.w;
            Vtlds[c0 +  8][j] = (bf16_t)b2.x; Vtlds[c0 +  9][j] = (bf16_t)b2.y;
            Vtlds[c0 + 10][j] = (bf16_t)b2.z; Vtlds[c0 + 11][j] = (bf16_t)b2.w;
            Vtlds[c0 + 12][j] = (bf16_t)b3.x; Vtlds[c0 + 13][j] = (bf16_t)b3.y;
            Vtlds[c0 + 14][j] = (bf16_t)b3.z; Vtlds[c0 + 15][j] = (bf16_t)b3.w;
        }
        __syncthreads();

        f32x4 s[4];
        #pragma unroll
        for (int ct = 0; ct < 4; ++ct) {
            f32x4 z = (f32x4){0.f, 0.f, 0.f, 0.f};
            #pragma unroll
            for (int ks = 0; ks < 2; ++ks) {
                bf16x8 kf = *(const bf16x8*)&Klds[ct * 16 + l15][ks * 32 + g * 8];
                z = MFMA16(qf[ks], kf, z);
            }
            s[ct] = z;
        }

        float lg[4][4];
        #pragma unroll
        for (int ct = 0; ct < 4; ++ct)
            #pragma unroll
            for (int r = 0; r < 4; ++r)
                lg[ct][r] = s[ct][r] * SCL2;

        if (needmask) {
            const int irow = q0 + wv * 16 + g * 4;
            #pragma unroll
            for (int ct = 0; ct < 4; ++ct) {
                const int j = k0 + ct * 16 + l15;
                #pragma unroll
                for (int r = 0; r < 4; ++r) {
                    int diff = irow + r - j;
                    diff = diff < 0 ? -diff : diff;
                    if (diff < MS) lg[ct][r] = -1e30f;
                }
            }
        }

        #pragma unroll
        for (int r = 0; r < 4; ++r) {
            float mx = fmaxf(fmaxf(lg[0][r], lg[1][r]), fmaxf(lg[2][r], lg[3][r]));
            #pragma unroll
            for (int off = 1; off < 16; off <<= 1) mx = fmaxf(mx, __shfl_xor(mx, off));
            const float mnew = fmaxf(m2[r], mx);
            const float c = exp2f(m2[r] - mnew);
            m2[r] = mnew;
            #pragma unroll
            for (int ct = 0; ct < 4; ++ct) acc[ct][r] *= c;
            float ps = 0.f;
            #pragma unroll
            for (int ct = 0; ct < 4; ++ct) {
                float p = exp2f(lg[ct][r] - mnew);
                bf16_t pb = (bf16_t)p;
                Plds[wv][g * 4 + r][ct * 16 + l15] = pb;
                ps += (float)pb;
            }
            #pragma unroll
            for (int off = 1; off < 16; off <<= 1) ps += __shfl_xor(ps, off);
            lsum[r] = lsum[r] * c + ps;
        }

        __syncthreads();

        #pragma unroll
        for (int ks = 0; ks < 2; ++ks) {
            bf16x8 pfr = *(const bf16x8*)&Plds[wv][l15][ks * 32 + g * 8];
            #pragma unroll
            for (int ct = 0; ct < 4; ++ct) {
                bf16x8 vfl = *(const bf16x8*)&Vtlds[ct * 16 + l15][ks * 32 + g * 8];
                acc[ct] = MFMA16(pfr, vfl, acc[ct]);
            }
        }
    }

    #pragma unroll
    for (int r = 0; r < 4; ++r) {
        const float inv = 1.0f / lsum[r];
        const size_t row = (size_t)(b * Ll + q0 + wv * 16 + g * 4 + r);
        float* op = O + (row * Hh + h) * Dd;
        #pragma unroll
        for (int ct = 0; ct < 4; ++ct)
            op[ct * 16 + l15] = acc[ct][r] * inv;
    }
}

extern "C" void kernel_launch(void* const* d_in, const int* in_sizes, int n_in,
                              void* d_out, int out_size, void* d_ws, size_t ws_size,
                              hipStream_t stream) {
    const float* Q = (const float*)d_in[0];
    const float* K = (const float*)d_in[1];
    const float* V = (const float*)d_in[2];
    float* O = (float*)d_out;

    const size_t nelem = (size_t)Bb * Hh * Ll * Ee;      // 4.19M per tensor
    const size_t need  = nelem * 2 * 2;                  // Kb + Vt bf16

    if (ws_size >= need) {
        bf16_t* Kb = (bf16_t*)d_ws;
        bf16_t* Vt = Kb + nelem;
        prep<<<dim3(3072), dim3(256), 0, stream>>>(K, V, Kb, Vt);
        fattn10<<<dim3(256), dim3(512), 0, stream>>>(Q, Kb, Vt, O);
    } else {
        fattn_f32<<<dim3(Bb * Hh * 32), dim3(256), 0, stream>>>(Q, K, V, O);
    }
}

// Round 12
// 57.880 us; speedup vs baseline: 2.1741x; 1.0944x over previous
//
#include <hip/hip_runtime.h>
#include <hip/hip_bf16.h>

typedef __bf16 bf16_t;
typedef __bf16 bf16x8 __attribute__((ext_vector_type(8)));
typedef float f32x4 __attribute__((ext_vector_type(4)));
typedef float f32x16 __attribute__((ext_vector_type(16)));
typedef unsigned int u32;

#define MFMA16(A,B,C) __builtin_amdgcn_mfma_f32_16x16x32_bf16(A,B,C,0,0,0)
#define MFMA32(A,B,C) __builtin_amdgcn_mfma_f32_32x32x16_bf16(A,B,C,0,0,0)

constexpr int Bb = 4, Ll = 2048, Hh = 8, Ee = 64, Dd = 64;
constexpr int LDP = 72;   // prep/fallback kernels only
constexpr int MS = 128;   // band half-width (masked to -inf inside band)

static __device__ __forceinline__ bf16x8 cvt8(float4 a, float4 b) {
    bf16x8 t;
    t[0] = (bf16_t)a.x; t[1] = (bf16_t)a.y; t[2] = (bf16_t)a.z; t[3] = (bf16_t)a.w;
    t[4] = (bf16_t)b.x; t[5] = (bf16_t)b.y; t[6] = (bf16_t)b.z; t[7] = (bf16_t)b.w;
    return t;
}

static __device__ __forceinline__ u32 pkbf(float lo, float hi) {
    u32 d;
    asm("v_cvt_pk_bf16_f32 %0, %1, %2" : "=v"(d) : "v"(lo), "v"(hi));
    return d;
}

// raw v_exp_f32: inputs bounded (masked=-1e30 -> 0; live |s| <~ 30)
static __device__ __forceinline__ float fexp2(float x) {
    float r;
    asm("v_exp_f32 %0, %1" : "=v"(r) : "v"(x));
    return r;
}

static __device__ __forceinline__ f32x16 zero16() {
    f32x16 z;
    #pragma unroll
    for (int r = 0; r < 16; ++r) z[r] = 0.f;
    return z;
}

// ------ merged prep: K -> [b,h,l,e] bf16 ; V -> Vt [b,h,tile64,d,64] bf16 ---
__global__ __launch_bounds__(256) void prep(const float* __restrict__ K,
                                            const float* __restrict__ V,
                                            bf16_t* __restrict__ Kb,
                                            bf16_t* __restrict__ Vt) {
    __shared__ bf16_t VLp[Dd][LDP];
    if (blockIdx.x < 2048) {
        const int c = blockIdx.x * 256 + threadIdx.x;
        const int e0 = (c & 7) * 8;
        const int h  = (c >> 3) & (Hh - 1);
        const int l  = (c >> 6) & (Ll - 1);
        const int b  = c >> 17;
        const float* s = K + ((((size_t)b * Ll + l) * Hh + h) * Ee + e0);
        float4 f0 = ((const float4*)s)[0];
        float4 f1 = ((const float4*)s)[1];
        *(bf16x8*)(Kb + ((((size_t)b * Hh + h) * Ll + l) * Ee + e0)) = cvt8(f0, f1);
    } else {
        const int bb = blockIdx.x - 2048;
        const int bh = bb >> 5;
        const int t  = bb & 31;
        const int b = bh >> 3, h = bh & 7;
        {
            const int j  = threadIdx.x >> 2;
            const int d0 = (threadIdx.x & 3) * 16;
            const float* vp = V + (((size_t)(b * Ll + t * 64 + j)) * Hh + h) * Dd + d0;
            float4 x0 = ((const float4*)vp)[0], x1 = ((const float4*)vp)[1];
            float4 x2 = ((const float4*)vp)[2], x3 = ((const float4*)vp)[3];
            VLp[d0 +  0][j] = (bf16_t)x0.x; VLp[d0 +  1][j] = (bf16_t)x0.y;
            VLp[d0 +  2][j] = (bf16_t)x0.z; VLp[d0 +  3][j] = (bf16_t)x0.w;
            VLp[d0 +  4][j] = (bf16_t)x1.x; VLp[d0 +  5][j] = (bf16_t)x1.y;
            VLp[d0 +  6][j] = (bf16_t)x1.z; VLp[d0 +  7][j] = (bf16_t)x1.w;
            VLp[d0 +  8][j] = (bf16_t)x2.x; VLp[d0 +  9][j] = (bf16_t)x2.y;
            VLp[d0 + 10][j] = (bf16_t)x2.z; VLp[d0 + 11][j] = (bf16_t)x2.w;
            VLp[d0 + 12][j] = (bf16_t)x3.x; VLp[d0 + 13][j] = (bf16_t)x3.y;
            VLp[d0 + 14][j] = (bf16_t)x3.z; VLp[d0 + 15][j] = (bf16_t)x3.w;
        }
        __syncthreads();
        {
            const int d  = threadIdx.x >> 2;
            const int j0 = (threadIdx.x & 3) * 16;
            bf16x8 a0 = *(const bf16x8*)&VLp[d][j0];
            bf16x8 a1 = *(const bf16x8*)&VLp[d][j0 + 8];
            bf16_t* op = Vt + ((((size_t)bh * 32 + t) * 64 + d) * 64 + j0);
            *(bf16x8*)op = a0;
            *(bf16x8*)(op + 8) = a1;
        }
    }
}

// ---- main: BKV=128, 4 waves x 32 q-rows, pipelined S/sm/PV, lane-local psum
__global__ __launch_bounds__(256, 2) void fattn11(const float* __restrict__ Q,
                                                  const bf16_t* __restrict__ Kb,
                                                  const bf16_t* __restrict__ Vt,
                                                  float* __restrict__ O) {
    __shared__ __align__(16) bf16_t KL[2 * 8192];
    __shared__ __align__(16) bf16_t VL[2 * 8192];

    const int tid = threadIdx.x;
    const int ln  = tid & 63;
    const int wv  = tid >> 6;
    const int l31 = ln & 31;
    const int lh  = ln >> 5;

    // XCD swizzle: 8 XCDs x 64 blocks; each XCD owns 4 consecutive bh
    const int bid = blockIdx.x;
    const int x   = bid & 7;
    const int o   = bid >> 3;             // 0..63
    const int bh  = x * 4 + (o >> 4);     // 0..31
    const int qt  = o & 15;               // q-tile (128 rows)
    const int q0  = qt * 128;
    const int wq0 = q0 + wv * 32;
    const int qq  = wq0 + l31;            // this lane's query row
    const int b = bh >> 3, h = bh & 7;

    const bf16_t* kbase = Kb + (size_t)bh * (Ll * 64);
    const bf16_t* vbase = Vt + (size_t)bh * (Ll * 64);

    // Q fp32 -> scaled bf16 B-fragments (one-time)
    bf16x8 qreg[4];
    {
        const float SCL2 = 0.125f * 1.44269504f;
        const float* qp = Q + (((size_t)(b * Ll + qq)) * Hh + h) * Ee + lh * 8;
        #pragma unroll
        for (int ks = 0; ks < 4; ++ks) {
            float4 f0 = *(const float4*)(qp + ks * 16);
            float4 f1 = *(const float4*)(qp + ks * 16 + 4);
            f0.x *= SCL2; f0.y *= SCL2; f0.z *= SCL2; f0.w *= SCL2;
            f1.x *= SCL2; f1.y *= SCL2; f1.z *= SCL2; f1.w *= SCL2;
            qreg[ks] = cvt8(f0, f1);
        }
    }

    f32x16 acc0 = zero16(), acc1 = zero16();
    float psum = 0.f;   // lane-local partial row-sum for q-row qq (lh k-half)

    // staging: 256 threads x (4 K-chunks + 4 V-chunks) of 16B per 128-k tile.
    // Source pre-swizzled so the linear DMA realizes chunk ^= (row&7) in LDS.
    const int koff = (tid >> 3) * 64 + (((tid & 7) ^ ((tid >> 3) & 7)) << 3);
    const int ldst = tid * 8;

    #define STAGE(nxt, kt_) do {                                                     \
        const bf16_t* _k = kbase + (size_t)(kt_) * 8192 + koff;                      \
        const bf16_t* _v = vbase + (size_t)(kt_) * 8192 + koff;                      \
        bf16_t* _lk = KL + (nxt) * 8192 + ldst;                                      \
        bf16_t* _lv = VL + (nxt) * 8192 + ldst;                                      \
        _Pragma("unroll")                                                            \
        for (int _j = 0; _j < 4; ++_j) {                                             \
            __builtin_amdgcn_global_load_lds((const void*)(_k + _j * 2048),          \
                                             (void*)(_lk + _j * 2048), 16, 0, 0);    \
            __builtin_amdgcn_global_load_lds((const void*)(_v + _j * 2048),          \
                                             (void*)(_lv + _j * 2048), 16, 0, 0);    \
        }                                                                            \
    } while (0)

    // S for 32-k group g of the current tile
    #define SGRP(dst, g) do {                                                        \
        dst = zero16();                                                              \
        const int kb_ = bo + ((g) >> 1) * 4096 + (((g) & 1) * 32 + l31) * 64;        \
        __builtin_amdgcn_s_setprio(1);                                               \
        _Pragma("unroll")                                                            \
        for (int ks = 0; ks < 4; ++ks) {                                             \
            const int cc = (((2 * ks + lh) ^ (l31 & 7)) << 3);                       \
            bf16x8 ka = *(const bf16x8*)&KL[kb_ + cc];                               \
            dst = MFMA32(ka, qreg[ks], dst);                                         \
        }                                                                            \
        __builtin_amdgcn_s_setprio(0);                                               \
    } while (0)

    // mask + exp + psum-tree + pack + PV for group g (score vector sv)
    #define SMPV(g, sv) do {                                                         \
        const int kk0 = k0 + (g) * 32;                                               \
        const int dw = wq0 - kk0;                                                    \
        if (dw > -159 && dw < 159) {                                                 \
            _Pragma("unroll")                                                        \
            for (int r = 0; r < 16; ++r) {                                           \
                const int k = kk0 + 4 * lh + ((r & 3) + 8 * (r >> 2));               \
                const int dlt = qq - k;                                              \
                if (dlt > -MS && dlt < MS) sv[r] = -1e30f;                           \
            }                                                                        \
        }                                                                            \
        float p[16];                                                                 \
        _Pragma("unroll")                                                            \
        for (int r = 0; r < 16; ++r) p[r] = fexp2(sv[r]);                            \
        psum += (((p[0] + p[1]) + (p[2] + p[3])) +                                   \
                 ((p[4] + p[5]) + (p[6] + p[7]))) +                                  \
                (((p[8] + p[9]) + (p[10] + p[11])) +                                 \
                 ((p[12] + p[13]) + (p[14] + p[15])));                               \
        u32 x0 = pkbf(p[0], p[1]),   x1 = pkbf(p[2], p[3]);                          \
        u32 x2 = pkbf(p[4], p[5]),   x3 = pkbf(p[6], p[7]);                          \
        u32 x4 = pkbf(p[8], p[9]),   x5 = pkbf(p[10], p[11]);                        \
        u32 x6 = pkbf(p[12], p[13]), x7 = pkbf(p[14], p[15]);                        \
        asm volatile("v_permlane32_swap_b32 %0, %1" : "+v"(x0), "+v"(x2));           \
        asm volatile("v_permlane32_swap_b32 %0, %1" : "+v"(x1), "+v"(x3));           \
        asm volatile("v_permlane32_swap_b32 %0, %1" : "+v"(x4), "+v"(x6));           \
        asm volatile("v_permlane32_swap_b32 %0, %1" : "+v"(x5), "+v"(x7));           \
        union { u32 w[4]; bf16x8 v; } u0_, u1_;                                      \
        u0_.w[0] = x0; u0_.w[1] = x1; u0_.w[2] = x2; u0_.w[3] = x3;                  \
        u1_.w[0] = x4; u1_.w[1] = x5; u1_.w[2] = x6; u1_.w[3] = x7;                  \
        bf16x8 pf0 = u0_.v, pf1 = u1_.v;                                             \
        const int vb = bo + ((g) >> 1) * 4096;                                       \
        const int cA = (((4 * ((g) & 1) + lh) ^ (l31 & 7)) << 3);                    \
        const int cB = (((4 * ((g) & 1) + 2 + lh) ^ (l31 & 7)) << 3);                \
        bf16x8 vA0 = *(const bf16x8*)&VL[vb + l31 * 64 + cA];                        \
        bf16x8 vA1 = *(const bf16x8*)&VL[vb + (32 + l31) * 64 + cA];                 \
        bf16x8 vB0 = *(const bf16x8*)&VL[vb + l31 * 64 + cB];                        \
        bf16x8 vB1 = *(const bf16x8*)&VL[vb + (32 + l31) * 64 + cB];                 \
        __builtin_amdgcn_s_setprio(1);                                               \
        acc0 = MFMA32(pf0, vA0, acc0);                                               \
        acc1 = MFMA32(pf0, vA1, acc1);                                               \
        acc0 = MFMA32(pf1, vB0, acc0);                                               \
        acc1 = MFMA32(pf1, vB1, acc1);                                               \
        __builtin_amdgcn_s_setprio(0);                                               \
    } while (0)

    constexpr int NT = 15;     // 16 k-tiles of 128, exactly 1 (kt==qt) skipped

    STAGE(0, (0 >= qt ? 1 : 0));

    for (int i = 0; i < NT; ++i) {
        const int kt_ = i + (i >= qt ? 1 : 0);
        const int k0 = kt_ * 128;

        if (i + 1 < NT) {
            STAGE((i + 1) & 1, (i + 1) + ((i + 1) >= qt ? 1 : 0));
            asm volatile("s_waitcnt vmcnt(8)" ::: "memory");
        } else {
            asm volatile("s_waitcnt vmcnt(0)" ::: "memory");
        }
        __builtin_amdgcn_s_barrier();

        const int bo = (i & 1) * 8192;

        // pipelined: every softmax VALU burst sits between independent MFMA
        // clusters (S of the next group / PV of the previous)
        f32x16 sA, sB;
        SGRP(sA, 0);
        SGRP(sB, 1);
        SMPV(0, sA);
        SGRP(sA, 2);
        SMPV(1, sB);
        SGRP(sB, 3);
        SMPV(2, sA);
        SMPV(3, sB);

        __builtin_amdgcn_s_barrier();
    }
    #undef STAGE
    #undef SGRP
    #undef SMPV

    // ---- epilogue: lane-local psum -> full row sum -> normalize ----
    psum += __shfl_xor(psum, 32);          // combine the two lh k-halves
    const float inv = 1.0f / psum;         // lane l31 holds q-row wq0+l31's inv
    #pragma unroll
    for (int r = 0; r < 16; ++r) {
        const int rr = (r & 3) + 8 * (r >> 2) + 4 * lh;
        const float ir = __shfl(inv, rr);
        float* op = O + ((size_t)(b * Ll + wq0 + rr) * Hh + h) * Dd + l31;
        op[0]  = acc0[r] * ir;
        op[32] = acc1[r] * ir;
    }
}

// ---------------- fallback (fp32 inputs, online softmax, 16x16) -------------
__global__ __launch_bounds__(256, 2) void fattn_f32(const float* __restrict__ Q,
                                                    const float* __restrict__ K,
                                                    const float* __restrict__ V,
                                                    float* __restrict__ O) {
    __shared__ __align__(16) bf16_t Klds[64][LDP];
    __shared__ __align__(16) bf16_t Vtlds[Dd][LDP];
    __shared__ __align__(16) bf16_t Plds[4][16][LDP];

    const int tid = threadIdx.x;
    const int wv  = tid >> 6;
    const int ln  = tid & 63;
    const int l15 = ln & 15;
    const int g   = ln >> 4;

    const int nqt = Ll / 64;
    const int bid = blockIdx.x;
    const int qt  = bid % nqt;
    const int bh  = bid / nqt;
    const int b   = bh >> 3;
    const int h   = bh & 7;
    const int q0  = qt * 64;

    const float SCL2 = 0.125f * 1.44269504f;

    bf16x8 qf[2];
    {
        const float* qp = Q + (((size_t)(b * Ll + q0 + wv * 16 + l15)) * Hh + h) * Ee + g * 8;
        #pragma unroll
        for (int ks = 0; ks < 2; ++ks) {
            float4 f0 = *(const float4*)(qp + 32 * ks);
            float4 f1 = *(const float4*)(qp + 32 * ks + 4);
            qf[ks] = cvt8(f0, f1);
        }
    }

    f32x4 acc[4];
    #pragma unroll
    for (int ct = 0; ct < 4; ++ct) acc[ct] = (f32x4){0.f, 0.f, 0.f, 0.f};
    float m2[4], lsum[4];
    #pragma unroll
    for (int r = 0; r < 4; ++r) { m2[r] = -1e30f; lsum[r] = 0.f; }

    for (int k0 = 0; k0 < Ll; k0 += 64) {
        const int dd = k0 - q0;
        if (dd >= -64 && dd <= 64) continue;
        const bool needmask = (dd == 128) || (dd == -128);

        __syncthreads();
        {
            const int j  = tid >> 2;
            const int c0 = (tid & 3) << 4;
            const float* kp = K + (((size_t)(b * Ll + k0 + j)) * Hh + h) * Ee + c0;
            const float* vp = V + (((size_t)(b * Ll + k0 + j)) * Hh + h) * Dd + c0;
            float4 a0 = ((const float4*)kp)[0], a1 = ((const float4*)kp)[1];
            float4 a2 = ((const float4*)kp)[2], a3 = ((const float4*)kp)[3];
            *(bf16x8*)&Klds[j][c0]     = cvt8(a0, a1);
            *(bf16x8*)&Klds[j][c0 + 8] = cvt8(a2, a3);
            float4 b0 = ((const float4*)vp)[0], b1 = ((const float4*)vp)[1];
            float4 b2 = ((const float4*)vp)[2], b3 = ((const float4*)vp)[3];
            Vtlds[c0 +  0][j] = (bf16_t)b0.x; Vtlds[c0 +  1][j] = (bf16_t)b0.y;
            Vtlds[c0 +  2][j] = (bf16_t)b0.z; Vtlds[c0 +  3][j] = (bf16_t)b0.w;
            Vtlds[c0 +  4][j] = (bf16_t)b1.x; Vtlds[c0 +  5][j] = (bf16_t)b1.y;
            Vtlds[c0 +  6][j] = (bf16_t)b1.z; Vtlds[c0 +  7][j] = (bf16_t)b1.w;
            Vtlds[c0 +  8][j] = (bf16_t)b2.x; Vtlds[c0 +  9][j] = (bf16_t)b2.y;
            Vtlds[c0 + 10][j] = (bf16_t)b2.z; Vtlds[c0 + 11][j] = (bf16_t)b2.w;
            Vtlds[c0 + 12][j] = (bf16_t)b3.x; Vtlds[c0 + 13][j] = (bf16_t)b3.y;
            Vtlds[c0 + 14][j] = (bf16_t)b3.z; Vtlds[c0 + 15][j] = (bf16_t)b3.w;
        }
        __syncthreads();

        f32x4 s[4];
        #pragma unroll
        for (int ct = 0; ct < 4; ++ct) {
            f32x4 z = (f32x4){0.f, 0.f, 0.f, 0.f};
            #pragma unroll
            for (int ks = 0; ks < 2; ++ks) {
                bf16x8 kf = *(const bf16x8*)&Klds[ct * 16 + l15][ks * 32 + g * 8];
                z = MFMA16(qf[ks], kf, z);
            }
            s[ct] = z;
        }

        float lg[4][4];
        #pragma unroll
        for (int ct = 0; ct < 4; ++ct)
            #pragma unroll
            for (int r = 0; r < 4; ++r)
                lg[ct][r] = s[ct][r] * SCL2;

        if (needmask) {
            const int irow = q0 + wv * 16 + g * 4;
            #pragma unroll
            for (int ct = 0; ct < 4; ++ct) {
                const int j = k0 + ct * 16 + l15;
                #pragma unroll
                for (int r = 0; r < 4; ++r) {
                    int diff = irow + r - j;
                    diff = diff < 0 ? -diff : diff;
                    if (diff < MS) lg[ct][r] = -1e30f;
                }
            }
        }

        #pragma unroll
        for (int r = 0; r < 4; ++r) {
            float mx = fmaxf(fmaxf(lg[0][r], lg[1][r]), fmaxf(lg[2][r], lg[3][r]));
            #pragma unroll
            for (int off = 1; off < 16; off <<= 1) mx = fmaxf(mx, __shfl_xor(mx, off));
            const float mnew = fmaxf(m2[r], mx);
            const float c = exp2f(m2[r] - mnew);
            m2[r] = mnew;
            #pragma unroll
            for (int ct = 0; ct < 4; ++ct) acc[ct][r] *= c;
            float ps = 0.f;
            #pragma unroll
            for (int ct = 0; ct < 4; ++ct) {
                float p = exp2f(lg[ct][r] - mnew);
                bf16_t pb = (bf16_t)p;
                Plds[wv][g * 4 + r][ct * 16 + l15] = pb;
                ps += (float)pb;
            }
            #pragma unroll
            for (int off = 1; off < 16; off <<= 1) ps += __shfl_xor(ps, off);
            lsum[r] = lsum[r] * c + ps;
        }

        __syncthreads();

        #pragma unroll
        for (int ks = 0; ks < 2; ++ks) {
            bf16x8 pfr = *(const bf16x8*)&Plds[wv][l15][ks * 32 + g * 8];
            #pragma unroll
            for (int ct = 0; ct < 4; ++ct) {
                bf16x8 vfl = *(const bf16x8*)&Vtlds[ct * 16 + l15][ks * 32 + g * 8];
                acc[ct] = MFMA16(pfr, vfl, acc[ct]);
            }
        }
    }

    #pragma unroll
    for (int r = 0; r < 4; ++r) {
        const float inv = 1.0f / lsum[r];
        const size_t row = (size_t)(b * Ll + q0 + wv * 16 + g * 4 + r);
        float* op = O + (row * Hh + h) * Dd;
        #pragma unroll
        for (int ct = 0; ct < 4; ++ct)
            op[ct * 16 + l15] = acc[ct][r] * inv;
    }
}

extern "C" void kernel_launch(void* const* d_in, const int* in_sizes, int n_in,
                              void* d_out, int out_size, void* d_ws, size_t ws_size,
                              hipStream_t stream) {
    const float* Q = (const float*)d_in[0];
    const float* K = (const float*)d_in[1];
    const float* V = (const float*)d_in[2];
    float* O = (float*)d_out;

    const size_t nelem = (size_t)Bb * Hh * Ll * Ee;      // 4.19M per tensor
    const size_t need  = nelem * 2 * 2;                  // Kb + Vt bf16

    if (ws_size >= need) {
        bf16_t* Kb = (bf16_t*)d_ws;
        bf16_t* Vt = Kb + nelem;
        prep<<<dim3(3072), dim3(256), 0, stream>>>(K, V, Kb, Vt);
        fattn11<<<dim3(512), dim3(256), 0, stream>>>(Q, Kb, Vt, O);
    } else {
        fattn_f32<<<dim3(Bb * Hh * 32), dim3(256), 0, stream>>>(Q, K, V, O);
    }
}